// Round 20
// baseline (316.016 us; speedup 1.0000x reference)
//
#include <hip/hip_runtime.h>

// ---------------------------------------------------------------------------
// EdgeLLMAttentionTRTNative: out = X @ (s*Wo@Wq)^T + kv_cache passthrough.
// Round 20: hide the kv copy INSIDE the fast gemm_n big GEMM (152us) as
// per-tile interleaved traffic: each of 1024 blocks copies 8192 float4
// (1 load + 1 store per thread per tile, tiles 0..32; load@T, store@T+1 so
// the per-tile VM(0) guarantees data landed -> zero added stalls). HBM has
// 3.5 TB/s headroom (2.7/6.3 used) -> copy ~free. Replaces R19's gemm8
// (+27us slower GEMM) and its +11us tail-copy cost. R11's epilogue failure
// was retirement-delay, not BW — interleaving avoids it.
// prep_fused (kv-less) + small gemm_n unchanged from R19 (verified).
// ---------------------------------------------------------------------------

typedef __attribute__((ext_vector_type(8))) __bf16 bf16x8;
typedef __attribute__((ext_vector_type(4))) float f32x4;

__device__ __forceinline__ unsigned short f2bf(float f) {
  union { float f; unsigned u; } v; v.f = f;
  unsigned r = v.u + 0x7fffu + ((v.u >> 16) & 1u);   // round-to-nearest-even
  return (unsigned short)(r >> 16);
}

__device__ __forceinline__ ushort4 cast4(float4 v) {
  ushort4 o;
  o.x = f2bf(v.x); o.y = f2bf(v.y); o.z = f2bf(v.z); o.w = f2bf(v.w);
  return o;
}

typedef const __attribute__((address_space(1))) void* gptr_t;
typedef __attribute__((address_space(3))) void* lptr_t;

__device__ __forceinline__ void gload16(const void* g, void* l) {
  __builtin_amdgcn_global_load_lds((gptr_t)g, (lptr_t)l, 16, 0, 0);
}

#define BAR   do { asm volatile("" ::: "memory"); __builtin_amdgcn_s_barrier(); asm volatile("" ::: "memory"); } while (0)
#define LGKM0 asm volatile("s_waitcnt lgkmcnt(0)" ::: "memory")
#define VM(n) asm volatile("s_waitcnt vmcnt(" #n ")" ::: "memory")
#define PRIO1 __builtin_amdgcn_s_setprio(1)
#define PRIO0 __builtin_amdgcn_s_setprio(0)

// ---------------------------------------------------------------------------
// prep_fused (kv-less, R19 verified): [0,2048) X cast; [2048,11264) Wq 32x32
// transpose-cast tiles; [11264,12288) Wo cast. 308 MB total.
// ---------------------------------------------------------------------------
__global__ __launch_bounds__(256)
void prep_fused(const float4* __restrict__ hs4, ushort4* __restrict__ Xb4,
                const float* __restrict__ Wq, ushort* __restrict__ WqT,
                const float4* __restrict__ Wo4, ushort4* __restrict__ Wob4) {
  __shared__ float tile[32][33];
  const int H = 3072;
  const int b = blockIdx.x;
  const int t = threadIdx.x;
  if (b < 2048) {
    const int base = b * 3072 + t;
#pragma unroll
    for (int k = 0; k < 12; ++k)
      Xb4[base + k * 256] = cast4(hs4[base + k * 256]);
  } else if (b < 11264) {
    const int id = b - 2048;                       // 0..9215 (96x96 tiles)
    const int tc = (id % 96) * 32;
    const int tr = (id / 96) * 32;
    const int lx = t & 31;
    const int ly = t >> 5;
#pragma unroll
    for (int i = 0; i < 32; i += 8)
      tile[ly + i][lx] = Wq[(size_t)(tr + ly + i) * H + (tc + lx)];
    __syncthreads();
#pragma unroll
    for (int i = 0; i < 32; i += 8)
      WqT[(size_t)(tc + ly + i) * H + (tr + lx)] = f2bf(tile[lx][ly + i]);
  } else {
    const int base = (b - 11264) * 2304 + t;
#pragma unroll
    for (int k = 0; k < 9; ++k)
      Wob4[base + k * 256] = cast4(Wo4[base + k * 256]);
  }
}

// ---------------------------------------------------------------------------
// gemm_n (R14/R15 verified) + optional per-tile interleaved kv copy.
// C = A(rows x K) * B(cols x K)^T. BM=128 BN=192 BK=64; 4 waves 2Mx2N
// (per-wave 64x96, acc[4][6]); LDS 2x40KB -> 2 blocks/CU; chunk-XOR swizzle.
// Per tile T (slot s=T&1): PhA {read kh0 frags; STAGE(T+1 -> s^1); LGKM0;
// 24 MFMA}; PhB {read kh1 frags; LGKM0; 24 MFMA; VM(0); BAR}.
// kv copy (kvd != null): block b owns float4s [b*8192, (b+1)*8192); thread
// copies 1 float4/tile: load@T (T<32), store@T+1 (data one full tile old,
// drained by T's VM(0) -> the store never waits). 1024 blocks x 8192 x 16B
// = 134_217_728 B = the whole kv_cache, exactly.
// ---------------------------------------------------------------------------
template <int OUT_BF16>
__global__ __launch_bounds__(256, 2)
void gemm_n(const ushort* __restrict__ A, const ushort* __restrict__ B,
            void* __restrict__ Cv, int N, int K, float scale,
            const float4* __restrict__ kvs, float4* __restrict__ kvd) {
  __shared__ __align__(16) char smem[81920];

  const int t    = threadIdx.x;        // 0..255
  const int w    = t >> 6;             // 0..3
  const int lane = t & 63;
  const int wr   = w >> 1;             // 0..1 (M: 64 rows each)
  const int wc   = w & 1;              // 0..1 (N: 96 cols each)
  const int fr   = lane & 15;
  const int g    = lane >> 4;          // 0..3

  // XCD-aware bijective swizzle: nwg % 8 == 0 (1024 / 384).
  const int nwg = gridDim.x;
  const int cpx = nwg >> 3;
  const int wg  = (blockIdx.x & 7) * cpx + (blockIdx.x >> 3);
  const int nbx = N / 192;
  const int bx  = wg % nbx, by = wg / nbx;
  const int rowBase = by * 128, colBase = bx * 192;

  // Staging: per 4KB region = 32 rows x 128B; wave w rows [w*8,w*8+8);
  // lane l row +(l>>3), stored chunk l&7 = logical (l&7)^(l>>3).
  const int sr   = lane >> 3;
  const int scol = ((lane & 7) ^ sr) << 3;
  const ushort* Ag = A + (size_t)(rowBase + w * 8 + sr) * K + scol;
  const ushort* Bg = B + (size_t)(colBase + w * 8 + sr) * K + scol;
  const int wofs = w << 10;            // per-wave LDS dest offset

#define SLOT(T) (((T) & 1) * 40960)
#define STAGE(kt) do {                                                  \
    char* d_ = smem + SLOT(kt) + wofs;                                  \
    const ushort* sa_ = Ag + (size_t)(kt) * 64;                         \
    gload16(sa_,                    d_);                                \
    gload16(sa_ + (size_t)32 * K,   d_ + 4096);                         \
    gload16(sa_ + (size_t)64 * K,   d_ + 8192);                         \
    gload16(sa_ + (size_t)96 * K,   d_ + 12288);                        \
    const ushort* sb_ = Bg + (size_t)(kt) * 64;                         \
    gload16(sb_,                    d_ + 16384);                        \
    gload16(sb_ + (size_t)32 * K,   d_ + 20480);                        \
    gload16(sb_ + (size_t)64 * K,   d_ + 24576);                        \
    gload16(sb_ + (size_t)96 * K,   d_ + 28672);                        \
    gload16(sb_ + (size_t)128 * K,  d_ + 32768);                        \
    gload16(sb_ + (size_t)160 * K,  d_ + 36864); } while (0)

  // Fragment reads: row stride 128B; logical chunk kh*4+g at XOR (fr&7).
  const int aBase = (wr * 64 + fr) * 128;
  const int bBase = 16384 + (wc * 96 + fr) * 128;
  const int cs0   = (g ^ (fr & 7)) << 4;            // kh=0
  const int cs1   = ((4 | g) ^ (fr & 7)) << 4;      // kh=1

#define READ_A(dst, so, CS) do {                                        \
    const char* p_ = smem + (so) + aBase + (CS);                        \
    dst[0] = *(const bf16x8*)(p_);                                      \
    dst[1] = *(const bf16x8*)(p_ + 2048);                               \
    dst[2] = *(const bf16x8*)(p_ + 4096);                               \
    dst[3] = *(const bf16x8*)(p_ + 6144); } while (0)
#define READ_B(dst, so, CS) do {                                        \
    const char* p_ = smem + (so) + bBase + (CS);                        \
    dst[0] = *(const bf16x8*)(p_);                                      \
    dst[1] = *(const bf16x8*)(p_ + 2048);                               \
    dst[2] = *(const bf16x8*)(p_ + 4096);                               \
    dst[3] = *(const bf16x8*)(p_ + 6144);                               \
    dst[4] = *(const bf16x8*)(p_ + 8192);                               \
    dst[5] = *(const bf16x8*)(p_ + 10240); } while (0)
#define MFMA24(A4, B6) do {                                             \
    _Pragma("unroll") for (int mi_ = 0; mi_ < 4; ++mi_)                 \
    _Pragma("unroll") for (int ni_ = 0; ni_ < 6; ++ni_)                 \
      acc[mi_][ni_] = __builtin_amdgcn_mfma_f32_16x16x32_bf16(          \
          A4[mi_], B6[ni_], acc[mi_][ni_], 0, 0, 0); } while (0)

  f32x4 acc[4][6];
#pragma unroll
  for (int m = 0; m < 4; ++m)
#pragma unroll
    for (int n = 0; n < 6; ++n)
      acc[m][n] = f32x4{0.f, 0.f, 0.f, 0.f};

  bf16x8 Af[4], Bf[6];
  float4 cp;
  const size_t cbase = (size_t)blockIdx.x * 8192 + t;

  const int nt = K >> 6;               // 48

  STAGE(0);
  VM(0);
  BAR;

  for (int T = 0; T < nt; ++T) {
    const int so = SLOT(T);
    // Interleaved kv copy: store T-1's float4 (landed: drained by T-1's
    // VM(0)), then issue this tile's load. 32 float4/thread over 33 tiles.
    if (kvd) {
      if (T >= 1 && T <= 32) kvd[cbase + (size_t)(T - 1) * 256] = cp;
      if (T < 32)            cp = kvs[cbase + (size_t)T * 256];
    }
    // PhA: kh0
    READ_A(Af, so, cs0);
    READ_B(Bf, so, cs0);
    if (T + 1 < nt) STAGE(T + 1);      // -> slot so^1 (readers drained T-1)
    LGKM0;
    PRIO1; MFMA24(Af, Bf); PRIO0;
    // PhB: kh1
    READ_A(Af, so, cs1);
    READ_B(Bf, so, cs1);
    LGKM0;
    PRIO1; MFMA24(Af, Bf); PRIO0;
    VM(0);                             // tile T+1 + copy ops landed
    BAR;                               // all waves done reading slot so
  }

#undef STAGE
#undef READ_A
#undef READ_B
#undef MFMA24
#undef SLOT

  // C/D layout: col = lane&15, row = (lane>>4)*4 + i
  const int orow = rowBase + wr * 64 + (g << 2);
  const int ocol = colBase + wc * 96 + fr;
#pragma unroll
  for (int mi = 0; mi < 4; ++mi)
#pragma unroll
    for (int ni = 0; ni < 6; ++ni)
#pragma unroll
      for (int i = 0; i < 4; ++i) {
        const size_t idx = (size_t)(orow + mi * 16 + i) * N + (ocol + ni * 16);
        float v = acc[mi][ni][i] * scale;
        if (OUT_BF16) ((ushort*)Cv)[idx] = f2bf(v);
        else          ((float*)Cv)[idx]  = v;
      }
}

extern "C" void kernel_launch(void* const* d_in, const int* in_sizes, int n_in,
                              void* d_out, int out_size, void* d_ws, size_t ws_size,
                              hipStream_t stream) {
  const float* hs = (const float*)d_in[0];   // (4,2048,3072)
  const float* kv = (const float*)d_in[4];   // (4,2,8,4096,128)
  const float* Wq = (const float*)d_in[5];   // (3072,3072) (d,h)
  const float* Wo = (const float*)d_in[8];   // (3072,3072) (o,d)

  const int M = 8192, H = 3072;
  const int OUT_ELEMS = M * H;
  const int nkv = in_sizes[4];               // 33_554_432 floats

  float* out = (float*)d_out;

  // Workspace (bf16): Xb 48MB, Wob 18MB, WqTb 18MB, Wb 18MB (if it fits).
  ushort* Xb   = (ushort*)d_ws;
  ushort* Wob  = Xb + (size_t)M * H;
  ushort* WqTb = Wob + (size_t)H * H;
  const size_t WS_NEED = 2ull * ((size_t)M * H + 3ull * (size_t)H * H);
  const bool ws_ok = ws_size >= WS_NEED;
  // Wb in ws when possible (enables fused kv copy); else in the d_out
  // kv-tail — then the fused copy is disabled (it would clobber Wb) and a
  // trailing memcpy does the passthrough.
  ushort* Wb = ws_ok ? (WqTb + (size_t)H * H) : (ushort*)(out + OUT_ELEMS);

  const float qk_scale = 0.08838834764831845f;  // 128^-0.5

  // 1) prep: X cast + Wq transpose-cast + Wo cast (308 MB).
  prep_fused<<<12288, 256, 0, stream>>>((const float4*)hs, (ushort4*)Xb,
                                        Wq, WqTb, (const float4*)Wo,
                                        (ushort4*)Wob);

  // 2) W = s * Wo @ Wq  (grid 24*16 = 384, 2 blocks/CU, 1 round).
  gemm_n<1><<<(H / 128) * (H / 192), 256, 0, stream>>>(
      Wob, WqTb, (void*)Wb, H, H, qk_scale, nullptr, nullptr);

  // 3) out = X @ W^T  (grid 64*16 = 1024 = 2/CU x 2 rounds exact) with the
  //    kv copy interleaved per-tile (1024 blocks x 8192 float4 = whole kv).
  const float4* kvs = ws_ok ? (const float4*)kv : nullptr;
  float4* kvd = ws_ok ? (float4*)(out + OUT_ELEMS) : nullptr;
  gemm_n<0><<<(M / 128) * (H / 192), 256, 0, stream>>>(
      Xb, Wb, (void*)out, H, H, 1.0f, kvs, kvd);

  // 4) fallback kv passthrough (only when Wb aliased the kv-tail).
  if (!ws_ok) {
    hipMemcpyAsync(out + OUT_ELEMS, kv, (size_t)nkv * sizeof(float),
                   hipMemcpyDeviceToDevice, stream);
  }
}

// Round 21
// 296.614 us; speedup vs baseline: 1.0654x; 1.0654x over previous
//
#include <hip/hip_runtime.h>

// ---------------------------------------------------------------------------
// EdgeLLMAttentionTRTNative: out = X @ (s*Wo@Wq)^T + kv_cache passthrough.
// Round 21 = Round 19 restored (session best, 298.07us). R20's per-tile
// interleaved copy regressed +55us (VM(0) waits on kv store acks + L2
// pollution); the only copy-hiding mechanism that measured positive is the
// idle-dispatch-tail ride: gemm8 (384 blocks, 1.5 rounds @ 1 blk/CU) leaves
// 128 CUs idle in round 2; 128 appended copy blocks move the 268MB kv there
// for +11us net. prep (308MB, BW floor) + small gemm_n (2 blk/CU) + gemm8
// (8-phase 256^2) all verified passing at their measured floors.
// ---------------------------------------------------------------------------

typedef __attribute__((ext_vector_type(8))) __bf16 bf16x8;
typedef __attribute__((ext_vector_type(4))) float f32x4;

__device__ __forceinline__ unsigned short f2bf(float f) {
  union { float f; unsigned u; } v; v.f = f;
  unsigned r = v.u + 0x7fffu + ((v.u >> 16) & 1u);   // round-to-nearest-even
  return (unsigned short)(r >> 16);
}

__device__ __forceinline__ ushort4 cast4(float4 v) {
  ushort4 o;
  o.x = f2bf(v.x); o.y = f2bf(v.y); o.z = f2bf(v.z); o.w = f2bf(v.w);
  return o;
}

typedef const __attribute__((address_space(1))) void* gptr_t;
typedef __attribute__((address_space(3))) void* lptr_t;

__device__ __forceinline__ void gload16(const void* g, void* l) {
  __builtin_amdgcn_global_load_lds((gptr_t)g, (lptr_t)l, 16, 0, 0);
}

#define BAR   do { asm volatile("" ::: "memory"); __builtin_amdgcn_s_barrier(); asm volatile("" ::: "memory"); } while (0)
#define LGKM0 asm volatile("s_waitcnt lgkmcnt(0)" ::: "memory")
#define VM(n) asm volatile("s_waitcnt vmcnt(" #n ")" ::: "memory")
#define PRIO1 __builtin_amdgcn_s_setprio(1)
#define PRIO0 __builtin_amdgcn_s_setprio(0)

// ---------------------------------------------------------------------------
// prep_fused: [0,2048) X cast; [2048,11264) Wq 32x32 transpose-cast tiles;
// [11264,12288) Wo cast. 308 MB total (BW-floor ~50us).
// ---------------------------------------------------------------------------
__global__ __launch_bounds__(256)
void prep_fused(const float4* __restrict__ hs4, ushort4* __restrict__ Xb4,
                const float* __restrict__ Wq, ushort* __restrict__ WqT,
                const float4* __restrict__ Wo4, ushort4* __restrict__ Wob4) {
  __shared__ float tile[32][33];
  const int H = 3072;
  const int b = blockIdx.x;
  const int t = threadIdx.x;
  if (b < 2048) {
    const int base = b * 3072 + t;
#pragma unroll
    for (int k = 0; k < 12; ++k)
      Xb4[base + k * 256] = cast4(hs4[base + k * 256]);
  } else if (b < 11264) {
    const int id = b - 2048;                       // 0..9215 (96x96 tiles)
    const int tc = (id % 96) * 32;
    const int tr = (id / 96) * 32;
    const int lx = t & 31;
    const int ly = t >> 5;
#pragma unroll
    for (int i = 0; i < 32; i += 8)
      tile[ly + i][lx] = Wq[(size_t)(tr + ly + i) * H + (tc + lx)];
    __syncthreads();
#pragma unroll
    for (int i = 0; i < 32; i += 8)
      WqT[(size_t)(tc + ly + i) * H + (tr + lx)] = f2bf(tile[lx][ly + i]);
  } else {
    const int base = (b - 11264) * 2304 + t;
#pragma unroll
    for (int k = 0; k < 9; ++k)
      Wob4[base + k * 256] = cast4(Wo4[base + k * 256]);
  }
}

// ---------------------------------------------------------------------------
// gemm8 (R16 GEMM path, verified) + tail kv-copy blocks.
// GEMM: C(f32) = A(MxK)*B(NxK)^T, BM=BN=256 BK=64, 512 thr (8 waves 2Mx4N,
// per-wave 128x64, acc[8][4]); LDS 128KB = 2 bufs x 4 x 16KB halves;
// 8 phases / 2 tiles; vmcnt(4)@ph4/ph8; chunk-XOR swizzle.
// Blocks [ngemm, ngemm+128): copy 65536 float4 of kv each (runs on the
// idle CUs of the GEMM's tail round; independent work, no barriers).
// ---------------------------------------------------------------------------
__global__ __launch_bounds__(512, 2)
void gemm8(const ushort* __restrict__ A, const ushort* __restrict__ B,
           float* __restrict__ C, int N, int K, int ngemm,
           const float4* __restrict__ kvsrc, float4* __restrict__ kvdst) {
  __shared__ __align__(16) char smem[131072];

  if (blockIdx.x >= ngemm) {
    // kv-copy block: 65536 float4 (128 blocks x 65536 = 8_388_608 = all kv).
    const int cb = blockIdx.x - ngemm;
    const int t = threadIdx.x;
    size_t base = (size_t)cb * 65536 + t;
#pragma unroll 4
    for (int k = 0; k < 128; ++k)
      kvdst[base + (size_t)k * 512] = kvsrc[base + (size_t)k * 512];
    return;
  }

  const int t    = threadIdx.x;
  const int w    = t >> 6;
  const int lane = t & 63;
  const int wr   = w >> 2;             // 0..1 (M half: 128 rows)
  const int wc   = w & 3;              // 0..3 (64-col slice)
  const int fr   = lane & 15;
  const int g    = lane >> 4;          // 0..3

  // XCD-aware bijective swizzle over the ngemm GEMM blocks (384 % 8 == 0).
  const int cpx = ngemm >> 3;
  const int wg  = (blockIdx.x & 7) * cpx + (blockIdx.x >> 3);
  const int nbx = N >> 8;              // 12
  const int bx  = wg % nbx, by = wg / nbx;
  const int rowBase = by * 256, colBase = bx * 256;

  // Staging: half = 128 rows x 128B = 16KB = 2 gloads x 8KB (64 rows).
  // Thread t: row t>>3, stored chunk t&7 holds logical (t&7)^((t>>3)&7).
  const int sr   = t >> 3;                          // 0..63
  const int scol = ((t & 7) ^ (sr & 7)) << 3;       // pre-swizzled col
  const ushort* Ag = A + (size_t)(rowBase + sr) * K + scol;
  const ushort* Bg = B + (size_t)(colBase + sr) * K + scol;
  const int wofs = w << 10;

#define BUF(T) (((T) & 1) * 65536)
#define STG(half_base, srcp, kt) do {                                   \
    char* d_ = smem + (half_base) + wofs;                               \
    const ushort* s_ = (srcp) + (size_t)(kt) * 64;                      \
    gload16(s_, d_); gload16(s_ + (size_t)64 * K, d_ + 8192); } while (0)
#define SA_LO(kt) STG(BUF(kt) +     0, Ag,                  kt)
#define SA_HI(kt) STG(BUF(kt) + 16384, Ag + (size_t)128 * K, kt)
#define SB_LO(kt) STG(BUF(kt) + 32768, Bg,                  kt)
#define SB_HI(kt) STG(BUF(kt) + 49152, Bg + (size_t)128 * K, kt)

  // Fragment reads: row stride 128B; logical chunk kh*4+g at XOR (fr&7).
  const int cs0 = (g ^ (fr & 7)) << 4;
  const int cs1 = ((4 | g) ^ (fr & 7)) << 4;
  const int aB  = wr * 16384 + fr * 128;
  const int bB  = 32768 + (wc >> 1) * 16384 + (wc & 1) * 8192 + fr * 128;

#define RD_A(bo, MH) do {                                               \
    const char* p_ = smem + (bo) + aB + (MH) * 8192;                    \
    a8[0] = *(const bf16x8*)(p_ + cs0);                                 \
    a8[1] = *(const bf16x8*)(p_ + 2048 + cs0);                          \
    a8[2] = *(const bf16x8*)(p_ + 4096 + cs0);                          \
    a8[3] = *(const bf16x8*)(p_ + 6144 + cs0);                          \
    a8[4] = *(const bf16x8*)(p_ + cs1);                                 \
    a8[5] = *(const bf16x8*)(p_ + 2048 + cs1);                          \
    a8[6] = *(const bf16x8*)(p_ + 4096 + cs1);                          \
    a8[7] = *(const bf16x8*)(p_ + 6144 + cs1); } while (0)
#define RD_B(dst, bo, NH) do {                                          \
    const char* p_ = smem + (bo) + bB + (NH) * 4096;                    \
    dst[0] = *(const bf16x8*)(p_ + cs0);                                \
    dst[1] = *(const bf16x8*)(p_ + 2048 + cs0);                         \
    dst[2] = *(const bf16x8*)(p_ + cs1);                                \
    dst[3] = *(const bf16x8*)(p_ + 2048 + cs1); } while (0)
#define MF16(MH, NH, bq) do {                                           \
    _Pragma("unroll") for (int mi_ = 0; mi_ < 4; ++mi_)                 \
    _Pragma("unroll") for (int ni_ = 0; ni_ < 2; ++ni_) {               \
      acc[(MH)*4+mi_][(NH)*2+ni_] = __builtin_amdgcn_mfma_f32_16x16x32_bf16( \
          a8[mi_], bq[ni_], acc[(MH)*4+mi_][(NH)*2+ni_], 0, 0, 0);      \
      acc[(MH)*4+mi_][(NH)*2+ni_] = __builtin_amdgcn_mfma_f32_16x16x32_bf16( \
          a8[4+mi_], bq[2+ni_], acc[(MH)*4+mi_][(NH)*2+ni_], 0, 0, 0); } } while (0)

  f32x4 acc[8][4];
#pragma unroll
  for (int m = 0; m < 8; ++m)
#pragma unroll
    for (int n = 0; n < 4; ++n)
      acc[m][n] = f32x4{0.f, 0.f, 0.f, 0.f};

  bf16x8 a8[8], Bq0[4], Bq1[4];

  const int nt = K >> 6;               // 48 (even)

  // Prologue: tile 0 all halves + tile 1's B halves; allow B(1) in flight.
  SA_LO(0); SA_HI(0); SB_LO(0); SB_HI(0);
  SB_LO(1); SB_HI(1);
  VM(4);
  BAR;

  for (int it = 0; it < nt / 2; ++it) {
    const int T   = 2 * it;
    const int bo0 = BUF(T), bo1 = BUF(T + 1);
    const bool s2 = (T + 2) < nt;
    // ph1: Q(0,0) of T; stage A_lo(T+1)
    RD_A(bo0, 0); RD_B(Bq0, bo0, 0);
    SA_LO(T + 1);
    BAR; LGKM0; PRIO1; MF16(0, 0, Bq0); PRIO0; BAR;
    // ph2: Q(0,1); stage A_hi(T+1)
    RD_B(Bq1, bo0, 1);
    SA_HI(T + 1);
    BAR; LGKM0; PRIO1; MF16(0, 1, Bq1); PRIO0; BAR;
    // ph3: Q(1,1); stage B_lo(T+2) (B(T) free after ph2)
    RD_A(bo0, 1);
    if (s2) SB_LO(T + 2);
    BAR; LGKM0; PRIO1; MF16(1, 1, Bq1); PRIO0; BAR;
    // ph4: Q(1,0); stage B_hi(T+2); tile-boundary vmcnt
    if (s2) SB_HI(T + 2);
    BAR; LGKM0; PRIO1; MF16(1, 0, Bq0); PRIO0;
    if (s2) { VM(4); } else { VM(0); }   // tile T+1 fully landed
    BAR;
    // ph5: Q(0,0) of T+1; stage A_lo(T+2) (A(T) free after ph3)
    RD_A(bo1, 0); RD_B(Bq0, bo1, 0);
    if (s2) SA_LO(T + 2);
    BAR; LGKM0; PRIO1; MF16(0, 0, Bq0); PRIO0; BAR;
    // ph6: Q(0,1); stage A_hi(T+2)
    RD_B(Bq1, bo1, 1);
    if (s2) SA_HI(T + 2);
    BAR; LGKM0; PRIO1; MF16(0, 1, Bq1); PRIO0; BAR;
    // ph7: Q(1,1); stage B_lo(T+3) (B(T+1) free after ph6)
    RD_A(bo1, 1);
    if (s2) SB_LO(T + 3);
    BAR; LGKM0; PRIO1; MF16(1, 1, Bq1); PRIO0; BAR;
    // ph8: Q(1,0); stage B_hi(T+3); tile-boundary vmcnt
    if (s2) SB_HI(T + 3);
    BAR; LGKM0; PRIO1; MF16(1, 0, Bq0); PRIO0;
    if (s2) VM(4);                       // tile T+2 fully landed
    BAR;
  }

#undef BUF
#undef STG
#undef SA_LO
#undef SA_HI
#undef SB_LO
#undef SB_HI
#undef RD_A
#undef RD_B
#undef MF16

  // C/D layout: col = lane&15, row = (lane>>4)*4 + i
  const int ocol = colBase + wc * 64 + fr;
#pragma unroll
  for (int r = 0; r < 8; ++r) {
    const int orow = rowBase + wr * 128 + (r >> 2) * 64 + (r & 3) * 16 + (g << 2);
#pragma unroll
    for (int c = 0; c < 4; ++c) {
      const int col = ocol + (c >> 1) * 32 + (c & 1) * 16;
#pragma unroll
      for (int i = 0; i < 4; ++i)
        C[(size_t)(orow + i) * N + col] = acc[r][c][i];
    }
  }
}

// ---------------------------------------------------------------------------
// gemm_n (R14/R15, verified) — small GEMM. BM=128 BN=192 BK=64, 4 waves
// 2Mx2N (per-wave 64x96), LDS 2x40KB -> 2 blocks/CU.
// ---------------------------------------------------------------------------
template <int OUT_BF16>
__global__ __launch_bounds__(256, 2)
void gemm_n(const ushort* __restrict__ A, const ushort* __restrict__ B,
            void* __restrict__ Cv, int N, int K, float scale) {
  __shared__ __align__(16) char smem[81920];

  const int t    = threadIdx.x;
  const int w    = t >> 6;
  const int lane = t & 63;
  const int wr   = w >> 1;
  const int wc   = w & 1;
  const int fr   = lane & 15;
  const int g    = lane >> 4;

  const int nwg = gridDim.x;
  const int cpx = nwg >> 3;
  const int wg  = (blockIdx.x & 7) * cpx + (blockIdx.x >> 3);
  const int nbx = N / 192;
  const int bx  = wg % nbx, by = wg / nbx;
  const int rowBase = by * 128, colBase = bx * 192;

  const int sr   = lane >> 3;
  const int scol = ((lane & 7) ^ sr) << 3;
  const ushort* Ag = A + (size_t)(rowBase + w * 8 + sr) * K + scol;
  const ushort* Bg = B + (size_t)(colBase + w * 8 + sr) * K + scol;
  const int wofs = w << 10;

#define SLOT(T) (((T) & 1) * 40960)
#define STAGE(kt) do {                                                  \
    char* d_ = smem + SLOT(kt) + wofs;                                  \
    const ushort* sa_ = Ag + (size_t)(kt) * 64;                         \
    gload16(sa_,                    d_);                                \
    gload16(sa_ + (size_t)32 * K,   d_ + 4096);                         \
    gload16(sa_ + (size_t)64 * K,   d_ + 8192);                         \
    gload16(sa_ + (size_t)96 * K,   d_ + 12288);                        \
    const ushort* sb_ = Bg + (size_t)(kt) * 64;                         \
    gload16(sb_,                    d_ + 16384);                        \
    gload16(sb_ + (size_t)32 * K,   d_ + 20480);                        \
    gload16(sb_ + (size_t)64 * K,   d_ + 24576);                        \
    gload16(sb_ + (size_t)96 * K,   d_ + 28672);                        \
    gload16(sb_ + (size_t)128 * K,  d_ + 32768);                        \
    gload16(sb_ + (size_t)160 * K,  d_ + 36864); } while (0)

  const int aBase = (wr * 64 + fr) * 128;
  const int bBase = 16384 + (wc * 96 + fr) * 128;
  const int cs0   = (g ^ (fr & 7)) << 4;
  const int cs1   = ((4 | g) ^ (fr & 7)) << 4;

#define READ_A(dst, so, CS) do {                                        \
    const char* p_ = smem + (so) + aBase + (CS);                        \
    dst[0] = *(const bf16x8*)(p_);                                      \
    dst[1] = *(const bf16x8*)(p_ + 2048);                               \
    dst[2] = *(const bf16x8*)(p_ + 4096);                               \
    dst[3] = *(const bf16x8*)(p_ + 6144); } while (0)
#define READ_B(dst, so, CS) do {                                        \
    const char* p_ = smem + (so) + bBase + (CS);                        \
    dst[0] = *(const bf16x8*)(p_);                                      \
    dst[1] = *(const bf16x8*)(p_ + 2048);                               \
    dst[2] = *(const bf16x8*)(p_ + 4096);                               \
    dst[3] = *(const bf16x8*)(p_ + 6144);                               \
    dst[4] = *(const bf16x8*)(p_ + 8192);                               \
    dst[5] = *(const bf16x8*)(p_ + 10240); } while (0)
#define MFMA24(A4, B6) do {                                             \
    _Pragma("unroll") for (int mi_ = 0; mi_ < 4; ++mi_)                 \
    _Pragma("unroll") for (int ni_ = 0; ni_ < 6; ++ni_)                 \
      acc[mi_][ni_] = __builtin_amdgcn_mfma_f32_16x16x32_bf16(          \
          A4[mi_], B6[ni_], acc[mi_][ni_], 0, 0, 0); } while (0)

  f32x4 acc[4][6];
#pragma unroll
  for (int m = 0; m < 4; ++m)
#pragma unroll
    for (int n = 0; n < 6; ++n)
      acc[m][n] = f32x4{0.f, 0.f, 0.f, 0.f};

  bf16x8 Af[4], Bf[6];

  const int nt = K >> 6;

  STAGE(0);
  VM(0);
  BAR;

  for (int T = 0; T < nt; ++T) {
    const int so = SLOT(T);
    READ_A(Af, so, cs0);
    READ_B(Bf, so, cs0);
    if (T + 1 < nt) STAGE(T + 1);
    LGKM0;
    PRIO1; MFMA24(Af, Bf); PRIO0;
    READ_A(Af, so, cs1);
    READ_B(Bf, so, cs1);
    LGKM0;
    PRIO1; MFMA24(Af, Bf); PRIO0;
    VM(0);
    BAR;
  }

#undef STAGE
#undef READ_A
#undef READ_B
#undef MFMA24
#undef SLOT

  const int orow = rowBase + wr * 64 + (g << 2);
  const int ocol = colBase + wc * 96 + fr;
#pragma unroll
  for (int mi = 0; mi < 4; ++mi)
#pragma unroll
    for (int ni = 0; ni < 6; ++ni)
#pragma unroll
      for (int i = 0; i < 4; ++i) {
        const size_t idx = (size_t)(orow + mi * 16 + i) * N + (ocol + ni * 16);
        float v = acc[mi][ni][i] * scale;
        if (OUT_BF16) ((ushort*)Cv)[idx] = f2bf(v);
        else          ((float*)Cv)[idx]  = v;
      }
}

extern "C" void kernel_launch(void* const* d_in, const int* in_sizes, int n_in,
                              void* d_out, int out_size, void* d_ws, size_t ws_size,
                              hipStream_t stream) {
  const float* hs = (const float*)d_in[0];   // (4,2048,3072)
  const float* kv = (const float*)d_in[4];   // (4,2,8,4096,128)
  const float* Wq = (const float*)d_in[5];   // (3072,3072) (d,h)
  const float* Wo = (const float*)d_in[8];   // (3072,3072) (o,d)

  const int M = 8192, H = 3072;
  const int OUT_ELEMS = M * H;
  const int nkv = in_sizes[4];               // 33_554_432 floats

  float* out = (float*)d_out;

  // Workspace (bf16): Xb 48MB, Wob 18MB, WqTb 18MB, Wb 18MB (if it fits).
  ushort* Xb   = (ushort*)d_ws;
  ushort* Wob  = Xb + (size_t)M * H;
  ushort* WqTb = Wob + (size_t)H * H;
  const size_t WS_NEED = 2ull * ((size_t)M * H + 3ull * (size_t)H * H);
  const bool ws_ok = ws_size >= WS_NEED;
  ushort* Wb = ws_ok ? (WqTb + (size_t)H * H) : (ushort*)(out + OUT_ELEMS);

  const float qk_scale = 0.08838834764831845f;  // 128^-0.5

  // 1) prep: X cast + Wq transpose-cast + Wo cast (308 MB).
  prep_fused<<<12288, 256, 0, stream>>>((const float4*)hs, (ushort4*)Xb,
                                        Wq, WqTb, (const float4*)Wo,
                                        (ushort4*)Wob);

  // 2) W = s * Wo @ Wq  (grid 24*16 = 384, 2 blocks/CU, 1 round).
  gemm_n<1><<<(H / 128) * (H / 192), 256, 0, stream>>>(
      Wob, WqTb, (void*)Wb, H, H, qk_scale);

  // 3) out = X @ W^T — 8-phase kernel, 384 GEMM blocks (1.5 rounds) +
  //    128 kv-copy blocks that ride the idle CUs of the tail round.
  const int ngemm = (M / 256) * (H / 256);   // 384
  const float4* kvs = ws_ok ? (const float4*)kv : nullptr;
  float4* kvd = ws_ok ? (float4*)(out + OUT_ELEMS) : nullptr;
  const int grid3 = ws_ok ? (ngemm + 128) : ngemm;
  gemm8<<<grid3, 512, 0, stream>>>(Xb, Wb, out, H, H, ngemm, kvs, kvd);

  // 4) fallback kv passthrough (only when Wb aliased the kv-tail).
  if (!ws_ok) {
    hipMemcpyAsync(out + OUT_ELEMS, kv, (size_t)nkv * sizeof(float),
                   hipMemcpyDeviceToDevice, stream);
  }
}